// Round 6
// baseline (70.498 us; speedup 1.0000x reference)
//
#include <hip/hip_runtime.h>
#include <hip/hip_bf16.h>

namespace {
constexpr int NB    = 64;
constexpr int V0d   = 40, V1d = 40, V2d = 200;
constexpr int VOL   = V0d * V1d * V2d;        // 320,000
constexpr int NC0   = 5, NC1 = 5, NC2 = 21;
constexpr int CELLS = NC0 * NC1 * NC2;        // 525
constexpr int M     = NB * CELLS;             // 33600
constexpr int C1MAX = 104, C2MAX = 120;
constexpr int KS    = 104 * C1MAX * C2MAX;    // 1,297,920 dense compact keys
constexpr int SEG   = 4096;
constexpr int NSEG  = (KS + SEG - 1) / SEG;   // 317
constexpr int KSP   = NSEG * SEG;             // 1,298,432 (padded)
constexpr int CHVOL = 1000;
constexpr int RPB   = 4;                      // ranks per k_out block
constexpr int NQ    = M / RPB;                // 8400 blocks
}

// Round through bf16 (expected outputs are bf16-rounded float32 values).
__device__ __forceinline__ float bf16r(float v) {
    return __bfloat162float(__float2bfloat16(v));
}

// compact dense index; strictly increasing in (c0,c1,c2) lexicographic order,
// identical ordering to the reference key (c0*65536 + c1*256 + c2).
__device__ __forceinline__ int enc(int c0, int c1, int c2) {
    return (c0 * C1MAX + c1) * C2MAX + c2;
}

__global__ void k_zero(int* __restrict__ P, int4* __restrict__ mask4) {
    int idx = blockIdx.x * blockDim.x + threadIdx.x;
    int stride = gridDim.x * blockDim.x;
    int4* p4 = reinterpret_cast<int4*>(P);
    const int n4 = KSP / 4;             // 324,608
    for (int i = idx; i < n4; i += stride) p4[i] = make_int4(0, 0, 0, 0);
    const int m4 = M * 8 / 16;          // 16,800 int4 covering mask[M] (u64)
    for (int i = idx; i < m4; i += stride) mask4[i] = make_int4(0, 0, 0, 0);
}

__global__ void k_mark(const int* __restrict__ loc, int* __restrict__ P) {
    int m = blockIdx.x * blockDim.x + threadIdx.x;
    if (m >= M) return;
    int b = m / CELLS, cell = m % CELLS;
    int i = cell / (NC1 * NC2), j = (cell / NC2) % NC1, k = cell % NC2;
    P[enc(loc[b * 3 + 0] / 10 + i, loc[b * 3 + 1] / 10 + j,
          loc[b * 3 + 2] / 10 + k)] = 1;
}

// in-place exclusive scan of each SEG-sized segment; block totals -> Bsums
__global__ __launch_bounds__(256) void k_scan_blocks(int* __restrict__ P,
                                                     int* __restrict__ Bsums) {
    int bid = blockIdx.x, t = threadIdx.x;
    int4* p4 = reinterpret_cast<int4*>(P + (size_t)bid * SEG + t * 16);
    int4 a = p4[0], b = p4[1], c = p4[2], d = p4[3];
    int v[16] = {a.x, a.y, a.z, a.w, b.x, b.y, b.z, b.w,
                 c.x, c.y, c.z, c.w, d.x, d.y, d.z, d.w};
    int s = 0;
#pragma unroll
    for (int e = 0; e < 16; ++e) s += v[e];
    __shared__ int sc[256];
    sc[t] = s;
    __syncthreads();
#pragma unroll
    for (int off = 1; off < 256; off <<= 1) {
        int x = (t >= off) ? sc[t - off] : 0;
        __syncthreads();
        sc[t] += x;
        __syncthreads();
    }
    int incl = sc[t];
    if (t == 255) Bsums[bid] = incl;
    int run = incl - s;
#pragma unroll
    for (int e = 0; e < 16; ++e) { int x = v[e]; v[e] = run; run += x; }
    p4[0] = make_int4(v[0], v[1], v[2], v[3]);
    p4[1] = make_int4(v[4], v[5], v[6], v[7]);
    p4[2] = make_int4(v[8], v[9], v[10], v[11]);
    p4[3] = make_int4(v[12], v[13], v[14], v[15]);
}

// single-block exclusive scan of Bsums[NSEG]; total unique count -> U[0]
__global__ __launch_bounds__(256) void k_scan_sums(int* __restrict__ Bsums,
                                                   int* __restrict__ U) {
    __shared__ int sc[256];
    __shared__ int carry_s;
    int t = threadIdx.x;
    if (t == 0) carry_s = 0;
    __syncthreads();
    for (int base = 0; base < NSEG; base += 256) {
        int idx = base + t;
        int vv = (idx < NSEG) ? Bsums[idx] : 0;
        sc[t] = vv;
        __syncthreads();
#pragma unroll
        for (int off = 1; off < 256; off <<= 1) {
            int x = (t >= off) ? sc[t - off] : 0;
            __syncthreads();
            sc[t] += x;
            __syncthreads();
        }
        int incl = sc[t];
        int carry = carry_s;
        if (idx < NSEG) Bsums[idx] = carry + incl - vv;
        __syncthreads();
        if (t == 255) carry_s = carry + incl;
        __syncthreads();
    }
    if (t == 0) U[0] = carry_s;
}

// rank every tile; record unique key per rank and the contributor batch mask
__global__ void k_slots(const int* __restrict__ loc, const int* __restrict__ P,
                        const int* __restrict__ Bsums, int* __restrict__ ukeys,
                        unsigned long long* __restrict__ mask) {
    int m = blockIdx.x * blockDim.x + threadIdx.x;
    if (m >= M) return;
    int b = m / CELLS, cell = m % CELLS;
    int i = cell / (NC1 * NC2), j = (cell / NC2) % NC1, k = cell % NC2;
    int d = enc(loc[b * 3 + 0] / 10 + i, loc[b * 3 + 1] / 10 + j,
                loc[b * 3 + 2] / 10 + k);
    int rank = P[d] + Bsums[d / SEG];   // global sorted position of this key
    ukeys[rank] = d;                     // same value from all writers
    atomicOr(&mask[rank], 1ull << b);    // order-independent -> deterministic
}

// 4 ranks per block, branchless straight-line gathers -> 16+ loads in flight.
// No LDS, no barriers; per-rank values are wave-uniform (s_load chains x4,
// independent -> overlapped). Stores: 4 independent float4 per thread.
__global__ __launch_bounds__(256) void k_out(const float* __restrict__ data,
                                             const int* __restrict__ loc,
                                             const int* __restrict__ ukeys,
                                             const unsigned long long* __restrict__ mask,
                                             const int* __restrict__ U,
                                             float* __restrict__ out,
                                             long long base_ul) {
    // bijective XCD swizzle on rank-quads: NQ = 8400 = 8 * 1050
    int orig = blockIdx.x;
    int q = (orig & 7) * (NQ / 8) + (orig >> 3);
    int r0 = q * RPB;
    int t = threadIdx.x;
    int U0 = U[0];

    // element decode (elems e0..e0+3 of the 1000-float chunk)
    int e0 = t * 4;
    int xj[4], yj[4], zj[4];
#pragma unroll
    for (int j = 0; j < 4; ++j) {
        int e = e0 + j;
        xj[j] = e / 100; yj[j] = (e / 10) % 10; zj[j] = e % 10;
    }

    float acc[RPB][4] = {};
    unsigned long long mk2[RPB];
    int c0v[RPB], c1v[RPB], c2v[RPB];
    bool vR[RPB];

    // straight-line: first (usually only) contributor of each rank
#pragma unroll
    for (int rk = 0; rk < RPB; ++rk) {
        int r = r0 + rk;
        bool valid = (r < U0);
        vR[rk] = valid;
        int d = valid ? ukeys[r] : 0;                       // uniform s_load
        unsigned long long mk = valid ? mask[r] : 0ull;     // uniform s_load
        int c0 = d / (C1MAX * C2MAX);
        int rem = d % (C1MAX * C2MAX);
        int c1 = rem / C2MAX, c2 = rem % C2MAX;
        c0v[rk] = c0; c1v[rk] = c1; c2v[rk] = c2;
        bool any = (mk != 0ull);
        int b = any ? __builtin_ctzll(mk) : 0;
        mk2[rk] = any ? (mk & (mk - 1)) : 0ull;
        int l0 = loc[b * 3 + 0], l1 = loc[b * 3 + 1], l2 = loc[b * 3 + 2];
        // poison offsets when no contributor -> all elems fail bounds check
        int o0 = any ? (c0 * 10 - l0) : -1000;
        int o1 = c1 * 10 - l1, o2 = c2 * 10 - l2;
        const float* db = data + (size_t)b * VOL;
#pragma unroll
        for (int j = 0; j < 4; ++j) {
            int p0 = o0 + xj[j], p1 = o1 + yj[j], p2 = o2 + zj[j];
            bool v = ((unsigned)p0 < (unsigned)V0d) &
                     ((unsigned)p1 < (unsigned)V1d) &
                     ((unsigned)p2 < (unsigned)V2d);
            int lin = (p0 * V1d + p1) * V2d + p2;
            lin = lin < 0 ? 0 : (lin > VOL - 1 ? VOL - 1 : lin);  // safe addr
            float val = db[lin];
            acc[rk][j] += v ? val : 0.f;
        }
    }

    // rare extra contributors (ascending b == numpy segment-sum order)
#pragma unroll
    for (int rk = 0; rk < RPB; ++rk) {
        unsigned long long mk = mk2[rk];
        while (mk) {
            int b = __builtin_ctzll(mk);
            mk &= mk - 1;
            int l0 = loc[b * 3 + 0], l1 = loc[b * 3 + 1], l2 = loc[b * 3 + 2];
            int o0 = c0v[rk] * 10 - l0, o1 = c1v[rk] * 10 - l1,
                o2 = c2v[rk] * 10 - l2;
            const float* db = data + (size_t)b * VOL;
#pragma unroll
            for (int j = 0; j < 4; ++j) {
                int p0 = o0 + xj[j], p1 = o1 + yj[j], p2 = o2 + zj[j];
                bool v = ((unsigned)p0 < (unsigned)V0d) &
                         ((unsigned)p1 < (unsigned)V1d) &
                         ((unsigned)p2 < (unsigned)V2d);
                int lin = (p0 * V1d + p1) * V2d + p2;
                lin = lin < 0 ? 0 : (lin > VOL - 1 ? VOL - 1 : lin);
                float val = db[lin];
                acc[rk][j] += v ? val : 0.f;
            }
        }
    }

    if (t < 250) {
#pragma unroll
        for (int rk = 0; rk < RPB; ++rk) {
            *reinterpret_cast<float4*>(out + (long long)(r0 + rk) * CHVOL + e0) =
                make_float4(bf16r(acc[rk][0]), bf16r(acc[rk][1]),
                            bf16r(acc[rk][2]), bf16r(acc[rk][3]));
        }
    }

    // fused uloc writes (output 1): lane t<4 writes row r0+t
    if (t < RPB) {
        bool v;
        int c0, c1, c2;
        if (t == 0)      { v = vR[0]; c0 = c0v[0]; c1 = c1v[0]; c2 = c2v[0]; }
        else if (t == 1) { v = vR[1]; c0 = c0v[1]; c1 = c1v[1]; c2 = c2v[1]; }
        else if (t == 2) { v = vR[2]; c0 = c0v[2]; c1 = c1v[2]; c2 = c2v[2]; }
        else             { v = vR[3]; c0 = c0v[3]; c1 = c1v[3]; c2 = c2v[3]; }
        float u0, u1, u2;
        if (v) {
            u0 = (float)(c0 * 10);
            u1 = (float)(c1 * 10);
            u2 = (float)(c2 * 10);
        } else {  // jnp.unique fill 2^31-1 decoded: (327670, 2550, 2550)
            u0 = 327670.f; u1 = 2550.f; u2 = 2550.f;
        }
        long long i = base_ul + (long long)(r0 + t) * 3;
        out[i + 0] = bf16r(u0);
        out[i + 1] = bf16r(u1);
        out[i + 2] = bf16r(u2);
    }
}

extern "C" void kernel_launch(void* const* d_in, const int* in_sizes, int n_in,
                              void* d_out, int out_size, void* d_ws, size_t ws_size,
                              hipStream_t stream) {
    const float* data = (const float*)d_in[0];
    const int* loc    = (const int*)d_in[1];
    float* out        = (float*)d_out;

    const size_t bytesP  = (size_t)KSP * 4;                         // 5.19 MB
    const size_t bytesSm = (size_t)M * 8                            // mask
                         + (size_t)(NSEG + 64) * 4                  // Bsums+pad
                         + (size_t)M * 4 + 64;                      // ukeys, U
                                                                    // ~405 KB
    char* ws = (char*)d_ws;
    int* P;
    char* smalls;
    if (ws_size >= bytesP + bytesSm) {
        P      = (int*)ws;
        smalls = ws + bytesP;
    } else {
        // Fallback: dense array lives in the head of output 0 (dead before
        // k_out, the only later writer of that region).
        P      = (int*)d_out;
        smalls = ws;
    }
    unsigned long long* mask = (unsigned long long*)smalls;         // 8B-aligned
    int* Bsums = (int*)(smalls + (size_t)M * 8);
    int* ukeys = Bsums + NSEG + 64;
    int* U     = ukeys + M;

    long long out_sz  = (long long)out_size;                // 33,700,800 floats
    long long base_ul = out_sz - (long long)3 * M;          // 33,600,000

    k_zero<<<640, 256, 0, stream>>>(P, (int4*)mask);
    k_mark<<<(M + 255) / 256, 256, 0, stream>>>(loc, P);
    k_scan_blocks<<<NSEG, 256, 0, stream>>>(P, Bsums);
    k_scan_sums<<<1, 256, 0, stream>>>(Bsums, U);
    k_slots<<<(M + 255) / 256, 256, 0, stream>>>(loc, P, Bsums, ukeys, mask);
    k_out<<<NQ, 256, 0, stream>>>(data, loc, ukeys, mask, U, out, base_ul);
}

// Round 7
// 63.958 us; speedup vs baseline: 1.1022x; 1.1022x over previous
//
#include <hip/hip_runtime.h>
#include <hip/hip_bf16.h>

namespace {
constexpr int NB    = 64;
constexpr int V0d   = 40, V1d = 40, V2d = 200;
constexpr int VOL   = V0d * V1d * V2d;        // 320,000
constexpr int NC0   = 5, NC1 = 5, NC2 = 21;
constexpr int CELLS = NC0 * NC1 * NC2;        // 525
constexpr int M     = NB * CELLS;             // 33600
constexpr int C1MAX = 104, C2MAX = 120;
constexpr int KS    = 104 * C1MAX * C2MAX;    // 1,297,920 dense compact keys
constexpr int SEG   = 4096;
constexpr int NSEG  = (KS + SEG - 1) / SEG;   // 317
constexpr int KSP   = NSEG * SEG;             // 1,298,432 (padded)
constexpr int CHVOL = 1000;
}

// Round through bf16 (expected outputs are bf16-rounded float32 values).
__device__ __forceinline__ float bf16r(float v) {
    return __bfloat162float(__float2bfloat16(v));
}

// compact dense index; strictly increasing in (c0,c1,c2) lexicographic order,
// identical ordering to the reference key (c0*65536 + c1*256 + c2).
__device__ __forceinline__ int enc(int c0, int c1, int c2) {
    return (c0 * C1MAX + c1) * C2MAX + c2;
}

__global__ void k_zero(int* __restrict__ P, int4* __restrict__ mask4,
                       int4* __restrict__ desc4) {
    int idx = blockIdx.x * blockDim.x + threadIdx.x;
    int stride = gridDim.x * blockDim.x;
    int4* p4 = reinterpret_cast<int4*>(P);
    const int n4 = KSP / 4;             // 324,608
    for (int i = idx; i < n4; i += stride) p4[i] = make_int4(0, 0, 0, 0);
    const int m4 = M * 8 / 16;          // 16,800 int4 covering mask[M] (u64)
    for (int i = idx; i < m4; i += stride) mask4[i] = make_int4(0, 0, 0, 0);
    const int d4 = M * 4 / 16;          // 8,400 int4 covering desc[M] (u32)
    for (int i = idx; i < d4; i += stride) desc4[i] = make_int4(-1, -1, -1, -1);
}

__global__ void k_mark(const int* __restrict__ loc, int* __restrict__ P) {
    int m = blockIdx.x * blockDim.x + threadIdx.x;
    if (m >= M) return;
    int b = m / CELLS, cell = m % CELLS;
    int i = cell / (NC1 * NC2), j = (cell / NC2) % NC1, k = cell % NC2;
    P[enc(loc[b * 3 + 0] / 10 + i, loc[b * 3 + 1] / 10 + j,
          loc[b * 3 + 2] / 10 + k)] = 1;
}

// in-place exclusive scan of each SEG-sized segment; block totals -> Bsums
__global__ __launch_bounds__(256) void k_scan_blocks(int* __restrict__ P,
                                                     int* __restrict__ Bsums) {
    int bid = blockIdx.x, t = threadIdx.x;
    int4* p4 = reinterpret_cast<int4*>(P + (size_t)bid * SEG + t * 16);
    int4 a = p4[0], b = p4[1], c = p4[2], d = p4[3];
    int v[16] = {a.x, a.y, a.z, a.w, b.x, b.y, b.z, b.w,
                 c.x, c.y, c.z, c.w, d.x, d.y, d.z, d.w};
    int s = 0;
#pragma unroll
    for (int e = 0; e < 16; ++e) s += v[e];
    __shared__ int sc[256];
    sc[t] = s;
    __syncthreads();
#pragma unroll
    for (int off = 1; off < 256; off <<= 1) {
        int x = (t >= off) ? sc[t - off] : 0;
        __syncthreads();
        sc[t] += x;
        __syncthreads();
    }
    int incl = sc[t];
    if (t == 255) Bsums[bid] = incl;
    int run = incl - s;
#pragma unroll
    for (int e = 0; e < 16; ++e) { int x = v[e]; v[e] = run; run += x; }
    p4[0] = make_int4(v[0], v[1], v[2], v[3]);
    p4[1] = make_int4(v[4], v[5], v[6], v[7]);
    p4[2] = make_int4(v[8], v[9], v[10], v[11]);
    p4[3] = make_int4(v[12], v[13], v[14], v[15]);
}

// single-block exclusive scan of Bsums[NSEG]
__global__ __launch_bounds__(256) void k_scan_sums(int* __restrict__ Bsums) {
    __shared__ int sc[256];
    __shared__ int carry_s;
    int t = threadIdx.x;
    if (t == 0) carry_s = 0;
    __syncthreads();
    for (int base = 0; base < NSEG; base += 256) {
        int idx = base + t;
        int vv = (idx < NSEG) ? Bsums[idx] : 0;
        sc[t] = vv;
        __syncthreads();
#pragma unroll
        for (int off = 1; off < 256; off <<= 1) {
            int x = (t >= off) ? sc[t - off] : 0;
            __syncthreads();
            sc[t] += x;
            __syncthreads();
        }
        int incl = sc[t];
        int carry = carry_s;
        if (idx < NSEG) Bsums[idx] = carry + incl - vv;
        __syncthreads();
        if (t == 255) carry_s = carry + incl;
        __syncthreads();
    }
}

// rank every tile; record key, contributor bitmask, and packed first-
// contributor descriptor (atomicMin -> lowest batch wins, deterministic).
__global__ void k_slots(const int* __restrict__ loc, const int* __restrict__ P,
                        const int* __restrict__ Bsums, int* __restrict__ ukeys,
                        unsigned long long* __restrict__ mask,
                        unsigned int* __restrict__ desc) {
    int m = blockIdx.x * blockDim.x + threadIdx.x;
    if (m >= M) return;
    int b = m / CELLS, cell = m % CELLS;
    int i = cell / (NC1 * NC2), j = (cell / NC2) % NC1, k = cell % NC2;
    int l0 = loc[b * 3 + 0], l1 = loc[b * 3 + 1], l2 = loc[b * 3 + 2];
    int d = enc(l0 / 10 + i, l1 / 10 + j, l2 / 10 + k);
    int rank = P[d] + Bsums[d / SEG];   // global sorted position of this key
    ukeys[rank] = d;                     // same value from all writers
    atomicOr(&mask[rank], 1ull << b);    // order-independent -> deterministic
    // chunk-origin minus loc, biased +9: o0,o1 in [0,49], o2 in [0,209]
    unsigned int o0 = (unsigned int)(10 * i - l0 % 10 + 9);
    unsigned int o1 = (unsigned int)(10 * j - l1 % 10 + 9);
    unsigned int o2 = (unsigned int)(10 * k - l2 % 10 + 9);
    unsigned int pack = ((unsigned int)b << 24) | (o0 << 16) | (o1 << 8) | o2;
    atomicMin(&desc[rank], pack);        // lowest b wins == numpy first member
}

// one block per output slot. Single parallel scalar-load level (desc, mask,
// ukeys all independent), then the gather issues immediately. No LDS, no
// barriers. Thread t<250 owns float4 group [4t..4t+3] of the 1000-elem chunk.
__global__ __launch_bounds__(256) void k_out(const float* __restrict__ data,
                                             const int* __restrict__ loc,
                                             const int* __restrict__ ukeys,
                                             const unsigned long long* __restrict__ mask,
                                             const unsigned int* __restrict__ desc,
                                             float* __restrict__ out,
                                             long long base_ul) {
    // bijective XCD swizzle: M = 33600 = 8 * 4200 exactly
    int orig = blockIdx.x;
    int r = (orig & 7) * (M / 8) + (orig >> 3);
    int t = threadIdx.x;

    unsigned int dsc = desc[r];                  // uniform -> s_load (level 1)
    unsigned long long mk = mask[r];             // uniform -> s_load (level 1)
    int key = ukeys[r];                          // uniform -> s_load (level 1)
    bool valid = (dsc != 0xFFFFFFFFu);

    float ax = 0.f, ay = 0.f, az = 0.f, aw = 0.f;
    if (valid && t < 250) {
        int e0 = t * 4;
        int x  = e0 / 100;
        int rm = e0 % 100;
        int y  = rm / 10;
        int z0 = rm % 10;                        // in {0,2,4,6,8}
        // first contributor straight from the descriptor
        {
            int b  = (int)(dsc >> 24);
            int o0 = (int)((dsc >> 16) & 255) - 9;
            int o1 = (int)((dsc >> 8) & 255) - 9;
            int o2 = (int)(dsc & 255) - 9;
            const float* db = data + (size_t)b * VOL;
            if (z0 <= 6) {
                int p0 = o0 + x, p1 = o1 + y, p2 = o2 + z0;
                if ((unsigned)p0 < (unsigned)V0d &&
                    (unsigned)p1 < (unsigned)V1d) {
                    const float* s = db + (p0 * V1d + p1) * V2d + p2;
                    if (p2 >= 0 && p2 <= V2d - 4) {
                        ax += s[0]; ay += s[1]; az += s[2]; aw += s[3];
                    } else {
                        if ((unsigned)p2       < (unsigned)V2d) ax += s[0];
                        if ((unsigned)(p2 + 1) < (unsigned)V2d) ay += s[1];
                        if ((unsigned)(p2 + 2) < (unsigned)V2d) az += s[2];
                        if ((unsigned)(p2 + 3) < (unsigned)V2d) aw += s[3];
                    }
                }
            } else {
                float av[4] = {0.f, 0.f, 0.f, 0.f};
#pragma unroll
                for (int jj = 0; jj < 4; ++jj) {
                    int e  = e0 + jj;
                    int xx = e / 100;
                    int rj = e % 100;
                    int yy = rj / 10, zz = rj % 10;
                    int q0 = o0 + xx, q1 = o1 + yy, q2 = o2 + zz;
                    if ((unsigned)q0 < (unsigned)V0d &&
                        (unsigned)q1 < (unsigned)V1d &&
                        (unsigned)q2 < (unsigned)V2d)
                        av[jj] = db[(q0 * V1d + q1) * V2d + q2];
                }
                ax += av[0]; ay += av[1]; az += av[2]; aw += av[3];
            }
        }
        // rare extra contributors (ascending b == numpy segment-sum order;
        // lowest bit is the desc contributor -> clear it first)
        unsigned long long mke = mk & (mk - 1);
        while (mke) {
            int b = __builtin_ctzll(mke);
            mke &= mke - 1;
            int l0 = loc[b * 3 + 0], l1 = loc[b * 3 + 1], l2 = loc[b * 3 + 2];
            int rem = key % (C1MAX * C2MAX);
            int o0 = (key / (C1MAX * C2MAX)) * 10 - l0;
            int o1 = (rem / C2MAX) * 10 - l1;
            int o2 = (rem % C2MAX) * 10 - l2;
            const float* db = data + (size_t)b * VOL;
#pragma unroll
            for (int jj = 0; jj < 4; ++jj) {
                int e  = e0 + jj;
                int xx = e / 100;
                int rj = e % 100;
                int yy = rj / 10, zz = rj % 10;
                int q0 = o0 + xx, q1 = o1 + yy, q2 = o2 + zz;
                bool v = ((unsigned)q0 < (unsigned)V0d) &
                         ((unsigned)q1 < (unsigned)V1d) &
                         ((unsigned)q2 < (unsigned)V2d);
                int lin = (q0 * V1d + q1) * V2d + q2;
                lin = lin < 0 ? 0 : (lin > VOL - 1 ? VOL - 1 : lin);
                float val = db[lin];
                if (v) { if (jj==0) ax += val; else if (jj==1) ay += val;
                         else if (jj==2) az += val; else aw += val; }
            }
        }
    }

    if (t < 250) {
        // out + r*1000 floats = r*4000 B (16B aligned); +t*16 B -> aligned
        *reinterpret_cast<float4*>(out + (long long)r * CHVOL + t * 4) =
            make_float4(bf16r(ax), bf16r(ay), bf16r(az), bf16r(aw));
    }
    if (t == 0) {  // fused uloc write (output 1)
        float u0, u1, u2;
        if (valid) {
            int rem = key % (C1MAX * C2MAX);
            u0 = (float)((key / (C1MAX * C2MAX)) * 10);
            u1 = (float)((rem / C2MAX) * 10);
            u2 = (float)((rem % C2MAX) * 10);
        } else {  // jnp.unique fill 2^31-1 decoded: (327670, 2550, 2550)
            u0 = 327670.f; u1 = 2550.f; u2 = 2550.f;
        }
        long long i = base_ul + (long long)r * 3;
        out[i + 0] = bf16r(u0);
        out[i + 1] = bf16r(u1);
        out[i + 2] = bf16r(u2);
    }
}

extern "C" void kernel_launch(void* const* d_in, const int* in_sizes, int n_in,
                              void* d_out, int out_size, void* d_ws, size_t ws_size,
                              hipStream_t stream) {
    const float* data = (const float*)d_in[0];
    const int* loc    = (const int*)d_in[1];
    float* out        = (float*)d_out;

    const size_t bytesP  = (size_t)KSP * 4;                         // 5.19 MB
    const size_t bytesSm = (size_t)M * 8                            // mask
                         + (size_t)M * 4                            // desc
                         + (size_t)(NSEG + 64) * 4                  // Bsums+pad
                         + (size_t)M * 4 + 64;                      // ukeys
                                                                    // ~540 KB
    char* ws = (char*)d_ws;
    int* P;
    char* smalls;
    if (ws_size >= bytesP + bytesSm) {
        P      = (int*)ws;
        smalls = ws + bytesP;
    } else {
        // Fallback: dense array lives in the head of output 0 (dead before
        // k_out, the only later writer of that region).
        P      = (int*)d_out;
        smalls = ws;
    }
    unsigned long long* mask = (unsigned long long*)smalls;         // 8B-aligned
    unsigned int* desc = (unsigned int*)(smalls + (size_t)M * 8);
    int* Bsums = (int*)(smalls + (size_t)M * 8 + (size_t)M * 4);
    int* ukeys = Bsums + NSEG + 64;

    long long out_sz  = (long long)out_size;                // 33,700,800 floats
    long long base_ul = out_sz - (long long)3 * M;          // 33,600,000

    k_zero<<<640, 256, 0, stream>>>(P, (int4*)mask, (int4*)desc);
    k_mark<<<(M + 255) / 256, 256, 0, stream>>>(loc, P);
    k_scan_blocks<<<NSEG, 256, 0, stream>>>(P, Bsums);
    k_scan_sums<<<1, 256, 0, stream>>>(Bsums);
    k_slots<<<(M + 255) / 256, 256, 0, stream>>>(loc, P, Bsums, ukeys, mask, desc);
    k_out<<<M, 256, 0, stream>>>(data, loc, ukeys, mask, desc, out, base_ul);
}